// Round 6
// baseline (283.101 us; speedup 1.0000x reference)
//
#include <hip/hip_runtime.h>
#include <stdint.h>

#define B_   8
#define N_   2048
#define C_   128
#define EPS_ 0.1f

typedef __attribute__((ext_vector_type(8))) short short8;
typedef __attribute__((ext_vector_type(4))) float f32x4;

__device__ __forceinline__ unsigned short f2bf(float f) {
    union { float f; uint32_t u; } v; v.f = f;
    uint32_t u = v.u + 0x7FFF + ((v.u >> 16) & 1);   // RNE (inputs are finite)
    return (unsigned short)(u >> 16);
}

// ---------------- kernel 0: Wt[o][k] = bf16(W[k][o]) ----------------
__global__ __launch_bounds__(128) void k_wt(const float* __restrict__ W,
                                            unsigned short* __restrict__ Wt) {
    const int o = blockIdx.x, k = threadIdx.x;
    Wt[o * C_ + k] = f2bf(W[k * C_ + o]);
}

// ---- kernel 1: ht[b][o][j]=bf16(h), al/ar = h . w_att (MFMA x@W) ----
__global__ __launch_bounds__(256) void k_h(
    const float* __restrict__ x, const unsigned short* __restrict__ Wt,
    const float* __restrict__ wl, const float* __restrict__ wr,
    unsigned short* __restrict__ ht, float* __restrict__ al, float* __restrict__ ar)
{
    const int b    = blockIdx.x >> 5;
    const int i0   = (blockIdx.x & 31) * 64;
    const int t    = threadIdx.x;
    const int lane = t & 63;
    const int wid  = t >> 6;

    __shared__ __align__(16) unsigned short xs[64 * 128];
    __shared__ __align__(16) unsigned short ws[128 * 128];

    #pragma unroll
    for (int p = 0; p < 4; ++p) {
        const int s = p * 256 + t, row = s >> 4, u = s & 15;
        const float* gp = x + ((size_t)(b * N_ + i0 + row) * C_ + u * 8);
        float4 f0 = *(const float4*)gp;
        float4 f1 = *(const float4*)(gp + 4);
        short8 tv;
        tv[0] = (short)f2bf(f0.x); tv[1] = (short)f2bf(f0.y);
        tv[2] = (short)f2bf(f0.z); tv[3] = (short)f2bf(f0.w);
        tv[4] = (short)f2bf(f1.x); tv[5] = (short)f2bf(f1.y);
        tv[6] = (short)f2bf(f1.z); tv[7] = (short)f2bf(f1.w);
        *(short8*)&xs[row * 128 + (u ^ (row & 15)) * 8] = tv;
    }
    #pragma unroll
    for (int p = 0; p < 8; ++p) {
        const int s = p * 256 + t, o = s >> 4, u = s & 15;
        int4 v = *(const int4*)(Wt + o * C_ + u * 8);
        *(int4*)&ws[o * 128 + (u ^ (o & 15)) * 8] = v;
    }
    __syncthreads();

    const int m0 = wid * 16, lr = lane & 15, q = lane >> 4;
    f32x4 acc[8];
    #pragma unroll
    for (int i = 0; i < 8; ++i) acc[i] = (f32x4){0.f, 0.f, 0.f, 0.f};

    #pragma unroll
    for (int s = 0; s < 4; ++s) {
        const int m = m0 + lr;
        short8 af = *(const short8*)&xs[m * 128 + ((s * 4 + q) ^ (m & 15)) * 8];
        #pragma unroll
        for (int tt = 0; tt < 8; ++tt) {
            const int o = tt * 16 + lr;
            short8 bf = *(const short8*)&ws[o * 128 + ((s * 4 + q) ^ (o & 15)) * 8];
            acc[tt] = __builtin_amdgcn_mfma_f32_16x16x32_bf16(af, bf, acc[tt], 0, 0, 0);
        }
    }

    float pl[4] = {0.f, 0.f, 0.f, 0.f}, pr[4] = {0.f, 0.f, 0.f, 0.f};
    const int j0 = i0 + m0 + q * 4;
    #pragma unroll
    for (int tt = 0; tt < 8; ++tt) {
        const int o = tt * 16 + lr;
        const float wlv = wl[o], wrv = wr[o];
        unsigned int lo = (unsigned int)f2bf(acc[tt][0]) | ((unsigned int)f2bf(acc[tt][1]) << 16);
        unsigned int hi = (unsigned int)f2bf(acc[tt][2]) | ((unsigned int)f2bf(acc[tt][3]) << 16);
        uint2 u2; u2.x = lo; u2.y = hi;
        *(uint2*)&ht[((size_t)(b * C_ + o)) * N_ + j0] = u2;
        #pragma unroll
        for (int r = 0; r < 4; ++r) {
            pl[r] = fmaf(acc[tt][r], wlv, pl[r]);
            pr[r] = fmaf(acc[tt][r], wrv, pr[r]);
        }
    }
    #pragma unroll
    for (int msk = 1; msk < 16; msk <<= 1) {
        #pragma unroll
        for (int r = 0; r < 4; ++r) {
            pl[r] += __shfl_xor(pl[r], msk, 64);
            pr[r] += __shfl_xor(pr[r], msk, 64);
        }
    }
    if (lr == 0) {
        #pragma unroll
        for (int r = 0; r < 4; ++r) {
            al[b * N_ + j0 + r] = pl[r];
            ar[b * N_ + j0 + r] = pr[r];
        }
    }
}

// ---- kernel 2: out = mask(tanh(ar_i*al_j)) @ h + eps*x0 ----
// Barrier-free, LDS-free: A-fragments computed in-register, B-fragments
// loaded straight from ht (L2/L3-resident). 512 blocks x 256 thr, i-tile 32.
struct PrefO {                      // one 32-j k-step of per-lane operands
    int4   a0, a1;                  // adj[row][jb+q*8 .. +7]
    float4 l0, l1;                  // al  [jb+q*8 .. +7]
    int4   h0, h1, h2, h3;          // ht rows n0+{0,16,32,48}+r, 8 bf16 each
};

__global__ __launch_bounds__(256, 2) void k_out(
    const int* __restrict__ adj, const unsigned short* __restrict__ ht,
    const float* __restrict__ al, const float* __restrict__ ar,
    const float* __restrict__ x0, float* __restrict__ out)
{
    const int b    = blockIdx.x >> 6;
    const int i0   = (blockIdx.x & 63) * 32;
    const int t    = threadIdx.x;
    const int lane = t & 63;
    const int wid  = t >> 6;
    const int m0   = (wid & 1) * 16, n0 = (wid >> 1) * 64;
    const int r    = lane & 15, q = lane >> 4;

    const int row  = i0 + m0 + r;                       // A-frag m-row
    const float arv = ar[b * N_ + row];

    const int*            adjp = adj + ((size_t)(b * N_ + row)) * N_ + q * 8;
    const float*          alp  = al + b * N_ + q * 8;
    const unsigned short* hb   = ht + (size_t)b * C_ * N_ + q * 8;
    const unsigned short* hp0  = hb + (size_t)(n0 +  0 + r) * N_;
    const unsigned short* hp1  = hb + (size_t)(n0 + 16 + r) * N_;
    const unsigned short* hp2  = hb + (size_t)(n0 + 32 + r) * N_;
    const unsigned short* hp3  = hb + (size_t)(n0 + 48 + r) * N_;

    auto ld = [&](int s) -> PrefO {
        PrefO P; const int jb = s * 32;
        P.a0 = *(const int4*)(adjp + jb);
        P.a1 = *(const int4*)(adjp + jb + 4);
        P.l0 = *(const float4*)(alp + jb);
        P.l1 = *(const float4*)(alp + jb + 4);
        P.h0 = *(const int4*)(hp0 + jb);
        P.h1 = *(const int4*)(hp1 + jb);
        P.h2 = *(const int4*)(hp2 + jb);
        P.h3 = *(const int4*)(hp3 + jb);
        return P;
    };

    f32x4 acc[4];
    #pragma unroll
    for (int i = 0; i < 4; ++i) acc[i] = (f32x4){0.f, 0.f, 0.f, 0.f};

    auto step = [&](const PrefO& P) {
        const int*   av = (const int*)&P.a0;    // a0,a1 contiguous; const idx only
        const float* lv = (const float*)&P.l0;  // l0,l1 contiguous
        short8 af;
        #pragma unroll
        for (int e = 0; e < 8; ++e) {
            float z  = arv * lv[e];
            float ex = __expf(2.f * z);
            float th = 1.f - 2.f * __builtin_amdgcn_rcpf(ex + 1.f);
            af[e] = av[e] ? (short)f2bf(th) : (short)0;
        }
        acc[0] = __builtin_amdgcn_mfma_f32_16x16x32_bf16(af, *(const short8*)&P.h0, acc[0], 0, 0, 0);
        acc[1] = __builtin_amdgcn_mfma_f32_16x16x32_bf16(af, *(const short8*)&P.h1, acc[1], 0, 0, 0);
        acc[2] = __builtin_amdgcn_mfma_f32_16x16x32_bf16(af, *(const short8*)&P.h2, acc[2], 0, 0, 0);
        acc[3] = __builtin_amdgcn_mfma_f32_16x16x32_bf16(af, *(const short8*)&P.h3, acc[3], 0, 0, 0);
    };

    PrefO A = ld(0);
    PrefO Bp = ld(1);
    for (int it = 0; it < 32; ++it) {
        step(A);
        if (it < 31) A = ld(2 * it + 2);
        step(Bp);
        if (it < 31) Bp = ld(2 * it + 3);
    }

    // ---- epilogue: out = acc + eps*x0 (C-layout: col=lane&15, row=q*4+reg) ----
    #pragma unroll
    for (int tt = 0; tt < 4; ++tt) {
        const int o = n0 + tt * 16 + r;
        #pragma unroll
        for (int rr = 0; rr < 4; ++rr) {
            const int orow = i0 + m0 + q * 4 + rr;
            const size_t idx = ((size_t)(b * N_) + orow) * C_ + o;
            out[idx] = acc[tt][rr] + EPS_ * x0[idx];
        }
    }
}

extern "C" void kernel_launch(void* const* d_in, const int* in_sizes, int n_in,
                              void* d_out, int out_size, void* d_ws, size_t ws_size,
                              hipStream_t stream) {
    const float* x   = (const float*)d_in[0];
    const float* x0  = (const float*)d_in[1];
    const int*   adj = (const int*)d_in[2];
    const float* W   = (const float*)d_in[3];
    const float* wl  = (const float*)d_in[4];
    const float* wr  = (const float*)d_in[5];
    float* out = (float*)d_out;

    unsigned short* ht = (unsigned short*)d_ws;                      // 4 MB
    float* al = (float*)((char*)d_ws + (size_t)B_ * C_ * N_ * 2);
    float* ar = al + B_ * N_;
    unsigned short* Wt = (unsigned short*)(ar + B_ * N_);            // 32 KB

    k_wt <<<C_,             C_,  0, stream>>>(W, Wt);
    k_h  <<<B_ * (N_ / 64), 256, 0, stream>>>(x, Wt, wl, wr, ht, al, ar);
    k_out<<<B_ * (N_ / 32), 256, 0, stream>>>(adj, ht, al, ar, x0, out);
}